// Round 4
// baseline (425.982 us; speedup 1.0000x reference)
//
#include <hip/hip_runtime.h>
#include <math.h>

#define E_PER_B 73536
#define E_TOT   588288
#define NB 8
#define NN 384
#define NF 128

typedef __attribute__((ext_vector_type(8)))  __bf16 bf16x8;
typedef __attribute__((ext_vector_type(16))) float  f32x16;
typedef unsigned short ushort_t;

// ---- threefry2x32, JAX partitionable scheme -> gumbel ----
__device__ __forceinline__ float gumbel_noise(unsigned l) {
  unsigned x0 = 0u;
  unsigned x1 = l;
  const unsigned ks0 = 0u, ks1 = 42u, ks2 = 0x1BD11BDAu ^ 42u;
  x0 += ks0; x1 += ks1;
#define TF_R(r) { x0 += x1; x1 = (x1 << (r)) | (x1 >> (32 - (r))); x1 ^= x0; }
  TF_R(13) TF_R(15) TF_R(26) TF_R(6)
  x0 += ks1; x1 += ks2 + 1u;
  TF_R(17) TF_R(29) TF_R(16) TF_R(24)
  x0 += ks2; x1 += ks0 + 2u;
  TF_R(13) TF_R(15) TF_R(26) TF_R(6)
  x0 += ks0; x1 += ks1 + 3u;
  TF_R(17) TF_R(29) TF_R(16) TF_R(24)
  x0 += ks1; x1 += ks2 + 4u;
  TF_R(13) TF_R(15) TF_R(26) TF_R(6)
  x0 += ks2; x1 += ks0 + 5u;
#undef TF_R
  unsigned bits = x0 ^ x1;
  float u = __uint_as_float((bits >> 9) | 0x3f800000u) - 1.0f;
  u = fmaxf(u, 1.17549435e-38f);
  float t = (float)(-log((double)u));
  return (float)(-log((double)t));
}

// ---- fp32 -> bf16 hi/mid/lo split (RNE for hi/mid, trunc lo) ----
__device__ __forceinline__ void split3(float x, ushort_t& h, ushort_t& m, ushort_t& l) {
  unsigned u = __float_as_uint(x);
  unsigned th = (u + 0x7fffu + ((u >> 16) & 1u)) & 0xffff0000u;
  float hf = __uint_as_float(th);
  float r1 = x - hf;                       // exact (Sterbenz)
  unsigned u1 = __float_as_uint(r1);
  unsigned tm = (u1 + 0x7fffu + ((u1 >> 16) & 1u)) & 0xffff0000u;
  float mf = __uint_as_float(tm);
  float r2 = r1 - mf;                      // exact
  h = (ushort_t)(th >> 16);
  m = (ushort_t)(tm >> 16);
  l = (ushort_t)(__float_as_uint(r2) >> 16);
}

// ---------------- k0: fold LN2 affine into W3 ----------------
__global__ __launch_bounds__(128) void k0_fold(
    const float* __restrict__ g2, const float* __restrict__ bt2,
    const float* __restrict__ W3, const float* __restrict__ b3,
    float* __restrict__ w3g, float* __restrict__ d2c3) {
  __shared__ double red[256];
  int f = threadIdx.x;
  w3g[f] = g2[f] * W3[f];
  red[f]       = (double)g2[f]  * (double)W3[f];
  red[128 + f] = (double)bt2[f] * (double)W3[f];
  __syncthreads();
  if (f == 0) {
    double d2 = 0.0, c3 = 0.0;
    for (int i = 0; i < 128; ++i) { d2 += red[i]; c3 += red[128 + i]; }
    d2c3[0] = (float)d2;
    d2c3[1] = (float)(c3 + (double)b3[0]);
  }
}

// ---------------- k0b: pre-split W2 into packed lane-order B-fragments ----
// Bpk[p][nc][s][l][i] bf16, p=plane(h/m/l), nc=N-strip(4), s=kstep(8),
// l=lane(64), i=reg(8). Element = split_p(W2[k][col]),
// k = s*16 + (l>>5)*8 + i, col = nc*32 + (l&31).
__global__ __launch_bounds__(256) void k0b_split(
    const float* __restrict__ W2, ushort_t* __restrict__ Bpk) {
  int t = blockIdx.x * 256 + threadIdx.x;    // 0..16383
  int k = t >> 7, col = t & 127;
  float x = W2[k * 128 + col];
  ushort_t h, m, l;
  split3(x, h, m, l);
  int nc = col >> 5;
  int ln = (col & 31) + ((k >> 3) & 1) * 32;
  int s  = k >> 4;
  int i  = k & 7;
  int base = ((nc * 8 + s) * 64 + ln) * 8 + i;
  Bpk[base]             = h;
  Bpk[16384 + base]     = m;
  Bpk[2 * 16384 + base] = l;
}

// ---------------- k1: P = nodes@W1[:128], Q = nodes@W1[128:] ----------------
__global__ __launch_bounds__(128) void k1_pq(
    const float* __restrict__ nodes, const float* __restrict__ W1,
    float* __restrict__ P, float* __restrict__ Q) {
  __shared__ float x[128];
  int row = blockIdx.x;
  int f = threadIdx.x;
  x[f] = nodes[row * 128 + f];
  __syncthreads();
  float p = 0.f, q = 0.f;
#pragma unroll 4
  for (int k = 0; k < 128; ++k) {
    float xk = x[k];
    p += xk * W1[k * 128 + f];
    q += xk * W1[(128 + k) * 128 + f];
  }
  P[row * 128 + f] = p;
  Q[row * 128 + f] = q;
}

// ---------------- k2: fused edge MLP (MFMA bf16x3) -> logits ----------------
// 128 edges/block, 512 threads (8 waves). Wave w: N-strip nc=w&3,
// M-tiles mrow = 2*(w>>2)+{0,1} of 32x32. h1 stored as 3 bf16 planes in LDS
// with 16B-slot XOR swizzle. 6-product bf16 split GEMM vs fp32 reference.
__global__ __launch_bounds__(512) void k2_edges(
    const float* __restrict__ P, const float* __restrict__ Q,
    const float* __restrict__ b1, const float* __restrict__ g1,
    const float* __restrict__ bt1, const ushort_t* __restrict__ Bpk,
    const float* __restrict__ b2, const float* __restrict__ w3g,
    const float* __restrict__ d2c3, float* __restrict__ logits) {
  __shared__ __align__(16) unsigned char sPlanes[3 * 32768];  // h planes; epi buf aliases
  __shared__ unsigned smeta[128];
  float* sredE = (float*)sPlanes;                // [128 e][97 words] (49.7 KB)

  const int tid = threadIdx.x;

  // ================= phase A: h1 = LN1(relu(P[si]+Q[so]+b1)) =================
  {
    const int e = tid >> 2;          // edge 0..127
    const int q = tid & 3;           // k-quarter
    int g = blockIdx.x * 128 + e;
    int b = g / E_PER_B;
    int t0 = g - b * E_PER_B;
    int si = (int)((1.0 + sqrt(1.0 + 8.0 * (double)t0)) * 0.5);
    while (si * (si - 1) / 2 > t0) --si;
    while ((si + 1) * si / 2 <= t0) ++si;
    int so = t0 - si * (si - 1) / 2;
    if (q == 0) smeta[e] = (unsigned)((b * NN + si) * (NN - 1) + so);

    const float4* P4  = (const float4*)(P + (size_t)(b * NN + si) * 128) + q * 8;
    const float4* Q4  = (const float4*)(Q + (size_t)(b * NN + so) * 128) + q * 8;
    const float4* B14 = (const float4*)b1 + q * 8;
    float av[32];
    float sum = 0.f;
#pragma unroll
    for (int k4 = 0; k4 < 8; ++k4) {
      float4 p = P4[k4], qq = Q4[k4], bb = B14[k4];
      float v0 = fmaxf(p.x + qq.x + bb.x, 0.f);
      float v1 = fmaxf(p.y + qq.y + bb.y, 0.f);
      float v2 = fmaxf(p.z + qq.z + bb.z, 0.f);
      float v3 = fmaxf(p.w + qq.w + bb.w, 0.f);
      av[4 * k4 + 0] = v0; av[4 * k4 + 1] = v1;
      av[4 * k4 + 2] = v2; av[4 * k4 + 3] = v3;
      sum += v0 + v1 + v2 + v3;
    }
    sum += __shfl_xor(sum, 1);
    sum += __shfl_xor(sum, 2);
    float m = sum * 0.0078125f;
    float ss = 0.f;
#pragma unroll
    for (int j = 0; j < 32; ++j) { float dx = av[j] - m; ss += dx * dx; }
    ss += __shfl_xor(ss, 1);
    ss += __shfl_xor(ss, 2);
    float var = ss * 0.0078125f;
    float rs = 1.0f / sqrtf(var + 1e-5f);

    const float4* G14  = (const float4*)g1 + q * 8;
    const float4* BT14 = (const float4*)bt1 + q * 8;
#pragma unroll
    for (int k4 = 0; k4 < 8; ++k4) {
      float4 gg = G14[k4], bt = BT14[k4];
      av[4 * k4 + 0] = (av[4 * k4 + 0] - m) * rs * gg.x + bt.x;
      av[4 * k4 + 1] = (av[4 * k4 + 1] - m) * rs * gg.y + bt.y;
      av[4 * k4 + 2] = (av[4 * k4 + 2] - m) * rs * gg.z + bt.z;
      av[4 * k4 + 3] = (av[4 * k4 + 3] - m) * rs * gg.w + bt.w;
    }
    // split + pack + swizzled store: 4 groups of 8 bf16 per plane
    const unsigned esw = (unsigned)(e & 7);
#pragma unroll
    for (int jj = 0; jj < 4; ++jj) {
      unsigned ph[4], pm[4], pl[4];
#pragma unroll
      for (int ii = 0; ii < 4; ++ii) {
        ushort_t h0, m0, l0, h1x, m1x, l1x;
        split3(av[jj * 8 + 2 * ii],     h0, m0, l0);
        split3(av[jj * 8 + 2 * ii + 1], h1x, m1x, l1x);
        ph[ii] = (unsigned)h0 | ((unsigned)h1x << 16);
        pm[ii] = (unsigned)m0 | ((unsigned)m1x << 16);
        pl[ii] = (unsigned)l0 | ((unsigned)l1x << 16);
      }
      unsigned slot = (unsigned)(4 * q + jj) ^ esw;
      unsigned base = (unsigned)e * 256u + (slot << 4);
      *(uint4*)(sPlanes + base)              = make_uint4(ph[0], ph[1], ph[2], ph[3]);
      *(uint4*)(sPlanes + 32768 + base)      = make_uint4(pm[0], pm[1], pm[2], pm[3]);
      *(uint4*)(sPlanes + 2 * 32768 + base)  = make_uint4(pl[0], pl[1], pl[2], pl[3]);
    }
  }
  __syncthreads();

  // ================= GEMM: h1[128x128] @ W2[128x128], 6-product bf16 ========
  const int w  = tid >> 6;
  const int l  = tid & 63;
  const int nc = w & 3;              // N-strip
  const int mr0 = (w >> 2) * 2;      // first M-tile
  const unsigned lrow = (unsigned)(l & 31);
  const unsigned lk   = (unsigned)(l >> 5);

  f32x16 acc0, acc1;
#pragma unroll
  for (int i = 0; i < 16; ++i) { acc0[i] = 0.f; acc1[i] = 0.f; }

  const unsigned e0 = (unsigned)mr0 * 32u + lrow;
  const unsigned e1 = e0 + 32u;
  const unsigned rb0 = e0 * 256u, rb1 = e1 * 256u;
  const unsigned esw = e0 & 7u;      // e1&7 == e0&7
  const unsigned char* pl0 = sPlanes;
  const unsigned char* bpB = (const unsigned char*)Bpk + (unsigned)(nc * 8) * 1024u
                             + (unsigned)l * 16u;
#pragma unroll
  for (int s = 0; s < 8; ++s) {
    unsigned co = (((unsigned)(2 * s) + lk) ^ esw) << 4;
    bf16x8 a0h = *(const bf16x8*)(pl0 + rb0 + co);
    bf16x8 a0m = *(const bf16x8*)(pl0 + 32768 + rb0 + co);
    bf16x8 a0l = *(const bf16x8*)(pl0 + 2 * 32768 + rb0 + co);
    bf16x8 a1h = *(const bf16x8*)(pl0 + rb1 + co);
    bf16x8 a1m = *(const bf16x8*)(pl0 + 32768 + rb1 + co);
    bf16x8 a1l = *(const bf16x8*)(pl0 + 2 * 32768 + rb1 + co);
    bf16x8 bh = *(const bf16x8*)(bpB + (unsigned)s * 1024u);
    bf16x8 bm = *(const bf16x8*)(bpB + 32768 + (unsigned)s * 1024u);
    bf16x8 bl = *(const bf16x8*)(bpB + 2 * 32768 + (unsigned)s * 1024u);
    // smallest-first accumulation
    acc0 = __builtin_amdgcn_mfma_f32_32x32x16_bf16(a0m, bm, acc0, 0, 0, 0);
    acc0 = __builtin_amdgcn_mfma_f32_32x32x16_bf16(a0l, bh, acc0, 0, 0, 0);
    acc0 = __builtin_amdgcn_mfma_f32_32x32x16_bf16(a0h, bl, acc0, 0, 0, 0);
    acc0 = __builtin_amdgcn_mfma_f32_32x32x16_bf16(a0m, bh, acc0, 0, 0, 0);
    acc0 = __builtin_amdgcn_mfma_f32_32x32x16_bf16(a0h, bm, acc0, 0, 0, 0);
    acc0 = __builtin_amdgcn_mfma_f32_32x32x16_bf16(a0h, bh, acc0, 0, 0, 0);
    acc1 = __builtin_amdgcn_mfma_f32_32x32x16_bf16(a1m, bm, acc1, 0, 0, 0);
    acc1 = __builtin_amdgcn_mfma_f32_32x32x16_bf16(a1l, bh, acc1, 0, 0, 0);
    acc1 = __builtin_amdgcn_mfma_f32_32x32x16_bf16(a1h, bl, acc1, 0, 0, 0);
    acc1 = __builtin_amdgcn_mfma_f32_32x32x16_bf16(a1m, bh, acc1, 0, 0, 0);
    acc1 = __builtin_amdgcn_mfma_f32_32x32x16_bf16(a1h, bm, acc1, 0, 0, 0);
    acc1 = __builtin_amdgcn_mfma_f32_32x32x16_bf16(a1h, bh, acc1, 0, 0, 0);
  }
  __syncthreads();   // all A-reads done; planes memory now reusable as sredE

  // ================= epilogue: per-edge stats partials ======================
  {
    const int col = nc * 32 + (int)lrow;
    const float b2c = b2[col];
    const float w3c = w3g[col];
#pragma unroll
    for (int t = 0; t < 2; ++t) {
      const unsigned ebase = (unsigned)(mr0 + t) * 32u + 4u * lk;
#pragma unroll
      for (int r = 0; r < 16; ++r) {
        float a = t ? acc1[r] : acc0[r];
        float rr = fmaxf(a + b2c, 0.f);
        float s_ = rr, q_ = rr * rr, d_ = rr * w3c;
        s_ += __shfl_xor(s_, 1); s_ += __shfl_xor(s_, 2);
        q_ += __shfl_xor(q_, 1); q_ += __shfl_xor(q_, 2);
        d_ += __shfl_xor(d_, 1); d_ += __shfl_xor(d_, 2);
        if ((l & 3) == 0) {
          unsigned e = ebase + (unsigned)((r & 3) + 8 * (r >> 2));
          unsigned idx = e * 97u + (unsigned)(nc * 8 + (int)(lrow >> 2)) * 3u;
          sredE[idx]     = s_;
          sredE[idx + 1] = q_;
          sredE[idx + 2] = d_;
        }
      }
    }
  }
  __syncthreads();

  // ================= pass 2: LN2-fold + W3 -> logit =========================
  if (tid < 128) {
    float dd2 = d2c3[0], cc3 = d2c3[1];
    const float* rp = sredE + tid * 97;
    float s = 0.f, q = 0.f, d = 0.f;
#pragma unroll
    for (int j = 0; j < 32; ++j) {
      s += rp[3 * j];
      q += rp[3 * j + 1];
      d += rp[3 * j + 2];
    }
    float m2 = s * 0.0078125f;
    float var = fmaxf(q * 0.0078125f - m2 * m2, 0.f);
    float rs2 = 1.0f / sqrtf(var + 1e-5f);
    logits[smeta[tid]] = rs2 * d - m2 * rs2 * dd2 + cc3;
  }
}

// ---------------- kz: zero output ----------------
__global__ __launch_bounds__(256) void kz_zero(float4* __restrict__ out, int n4) {
  int i = blockIdx.x * 256 + threadIdx.x;
  if (i < n4) out[i] = make_float4(0.f, 0.f, 0.f, 0.f);
}

// ---------------- k3: per (b,i,sample) gumbel argmax -> out=1 ----------------
__global__ __launch_bounds__(320) void k3_argmax(
    const float* __restrict__ logits, float* __restrict__ out) {
  int blk = blockIdx.x;
  int b = blk / NN;
  int i = blk - b * NN;
  if (i == 0) return;                    // row 0's pick lands on the diagonal
  int s = threadIdx.x >> 6;              // sample 0..4 (one wave each)
  int lane = threadIdx.x & 63;
  const float* row = logits + (size_t)(b * NN + i) * (NN - 1);
  float best = -INFINITY;
  int bestj = 0x7fffffff;
  unsigned lbase = ((unsigned)((s * NB + b) * NN + i)) * (NN - 1);
  for (int j = lane; j < i; j += 64) {
    float v = row[j] + gumbel_noise(lbase + (unsigned)j);
    if (v > best) { best = v; bestj = j; }
  }
  for (int off = 32; off; off >>= 1) {
    float ov = __shfl_down(best, off);
    int oj = __shfl_down(bestj, off);
    if (ov > best || (ov == best && oj < bestj)) { best = ov; bestj = oj; }
  }
  if (lane == 0) out[((size_t)(b * NN) + i) * NN + bestj] = 1.0f;
}

// ---------------- launch ----------------
extern "C" void kernel_launch(void* const* d_in, const int* in_sizes, int n_in,
                              void* d_out, int out_size, void* d_ws, size_t ws_size,
                              hipStream_t stream) {
  const float* nodes = (const float*)d_in[0];
  const float* W1  = (const float*)d_in[1];
  const float* b1  = (const float*)d_in[2];
  const float* g1  = (const float*)d_in[3];
  const float* bt1 = (const float*)d_in[4];
  const float* W2  = (const float*)d_in[5];
  const float* b2  = (const float*)d_in[6];
  const float* g2  = (const float*)d_in[7];
  const float* bt2 = (const float*)d_in[8];
  const float* W3  = (const float*)d_in[9];
  const float* b3  = (const float*)d_in[10];

  float* ws     = (float*)d_ws;
  float* Pw     = ws;                 // 393216 floats
  float* Qw     = ws + 393216;        // 393216
  float* w3g    = ws + 786432;        // 128
  float* d2c3   = ws + 786560;        // 2
  float* logits = ws + 786688;        // 1176576
  ushort_t* Bpk = (ushort_t*)(ws + 1963264);  // 49152 bf16 = 96 KB

  hipLaunchKernelGGL(k0_fold, dim3(1), dim3(128), 0, stream, g2, bt2, W3, b3, w3g, d2c3);
  hipLaunchKernelGGL(k0b_split, dim3(64), dim3(256), 0, stream, W2, Bpk);
  hipLaunchKernelGGL(k1_pq, dim3(NB * NN), dim3(128), 0, stream, nodes, W1, Pw, Qw);
  hipLaunchKernelGGL(k2_edges, dim3(E_TOT / 128), dim3(512), 0, stream,
                     Pw, Qw, b1, g1, bt1, Bpk, b2, w3g, d2c3, logits);
  int n4 = out_size / 4;              // 294912
  hipLaunchKernelGGL(kz_zero, dim3((n4 + 255) / 256), dim3(256), 0, stream,
                     (float4*)d_out, n4);
  hipLaunchKernelGGL(k3_argmax, dim3(NB * NN), dim3(320), 0, stream, logits, (float*)d_out);
}

// Round 5
// 386.380 us; speedup vs baseline: 1.1025x; 1.1025x over previous
//
#include <hip/hip_runtime.h>
#include <math.h>

#define E_PER_B 73536
#define E_TOT   588288
#define NB 8
#define NN 384
#define NF 128
#define BLK_E 64

typedef __attribute__((ext_vector_type(8)))  __bf16 bf16x8;
typedef __attribute__((ext_vector_type(16))) float  f32x16;
typedef unsigned short ushort_t;

// ---- threefry2x32, JAX partitionable scheme -> gumbel ----
__device__ __forceinline__ float gumbel_noise(unsigned l) {
  unsigned x0 = 0u;
  unsigned x1 = l;
  const unsigned ks0 = 0u, ks1 = 42u, ks2 = 0x1BD11BDAu ^ 42u;
  x0 += ks0; x1 += ks1;
#define TF_R(r) { x0 += x1; x1 = (x1 << (r)) | (x1 >> (32 - (r))); x1 ^= x0; }
  TF_R(13) TF_R(15) TF_R(26) TF_R(6)
  x0 += ks1; x1 += ks2 + 1u;
  TF_R(17) TF_R(29) TF_R(16) TF_R(24)
  x0 += ks2; x1 += ks0 + 2u;
  TF_R(13) TF_R(15) TF_R(26) TF_R(6)
  x0 += ks0; x1 += ks1 + 3u;
  TF_R(17) TF_R(29) TF_R(16) TF_R(24)
  x0 += ks1; x1 += ks2 + 4u;
  TF_R(13) TF_R(15) TF_R(26) TF_R(6)
  x0 += ks2; x1 += ks0 + 5u;
#undef TF_R
  unsigned bits = x0 ^ x1;
  float u = __uint_as_float((bits >> 9) | 0x3f800000u) - 1.0f;
  u = fmaxf(u, 1.17549435e-38f);
  float t = (float)(-log((double)u));
  return (float)(-log((double)t));
}

// ---- fp32 -> bf16 hi/mid/lo split (RNE for hi/mid, trunc lo) ----
__device__ __forceinline__ void split3(float x, ushort_t& h, ushort_t& m, ushort_t& l) {
  unsigned u = __float_as_uint(x);
  unsigned th = (u + 0x7fffu + ((u >> 16) & 1u)) & 0xffff0000u;
  float hf = __uint_as_float(th);
  float r1 = x - hf;                       // exact (Sterbenz)
  unsigned u1 = __float_as_uint(r1);
  unsigned tm = (u1 + 0x7fffu + ((u1 >> 16) & 1u)) & 0xffff0000u;
  float mf = __uint_as_float(tm);
  float r2 = r1 - mf;                      // exact
  h = (ushort_t)(th >> 16);
  m = (ushort_t)(tm >> 16);
  l = (ushort_t)(__float_as_uint(r2) >> 16);
}

// ---------------- k0: fold LN2 affine into W3 ----------------
__global__ __launch_bounds__(128) void k0_fold(
    const float* __restrict__ g2, const float* __restrict__ bt2,
    const float* __restrict__ W3, const float* __restrict__ b3,
    float* __restrict__ w3g, float* __restrict__ d2c3) {
  __shared__ double red[256];
  int f = threadIdx.x;
  w3g[f] = g2[f] * W3[f];
  red[f]       = (double)g2[f]  * (double)W3[f];
  red[128 + f] = (double)bt2[f] * (double)W3[f];
  __syncthreads();
  if (f == 0) {
    double d2 = 0.0, c3 = 0.0;
    for (int i = 0; i < 128; ++i) { d2 += red[i]; c3 += red[128 + i]; }
    d2c3[0] = (float)d2;
    d2c3[1] = (float)(c3 + (double)b3[0]);
  }
}

// ---------------- k0b: pre-split W2 into packed lane-order B-fragments ----
// Bpk[p][nc][s][l][i] bf16, p=plane(h/m/l), nc=N-strip(4), s=kstep(8),
// l=lane(64), i=reg(8). Element = split_p(W2[k][col]),
// k = s*16 + (l>>5)*8 + i, col = nc*32 + (l&31).
__global__ __launch_bounds__(256) void k0b_split(
    const float* __restrict__ W2, ushort_t* __restrict__ Bpk) {
  int t = blockIdx.x * 256 + threadIdx.x;    // 0..16383
  int k = t >> 7, col = t & 127;
  float x = W2[k * 128 + col];
  ushort_t h, m, l;
  split3(x, h, m, l);
  int nc = col >> 5;
  int ln = (col & 31) + ((k >> 3) & 1) * 32;
  int s  = k >> 4;
  int i  = k & 7;
  int base = ((nc * 8 + s) * 64 + ln) * 8 + i;
  Bpk[base]             = h;
  Bpk[16384 + base]     = m;
  Bpk[2 * 16384 + base] = l;
}

// ---------------- k1: P = nodes@W1[:128], Q = nodes@W1[128:] ----------------
__global__ __launch_bounds__(128) void k1_pq(
    const float* __restrict__ nodes, const float* __restrict__ W1,
    float* __restrict__ P, float* __restrict__ Q) {
  __shared__ float x[128];
  int row = blockIdx.x;
  int f = threadIdx.x;
  x[f] = nodes[row * 128 + f];
  __syncthreads();
  float p = 0.f, q = 0.f;
#pragma unroll 4
  for (int k = 0; k < 128; ++k) {
    float xk = x[k];
    p += xk * W1[k * 128 + f];
    q += xk * W1[(128 + k) * 128 + f];
  }
  P[row * 128 + f] = p;
  Q[row * 128 + f] = q;
}

// ---------------- k2: fused edge MLP (MFMA bf16x3) -> logits ----------------
// 64 edges/block, 256 threads (4 waves) -> ~49.5 KB LDS -> 3 blocks/CU.
// Wave w handles N-strip nc=w, M-tiles {rows 0-31, 32-63}. Concurrent blocks
// sit in different phases -> latency hiding across barriers.
__global__ __launch_bounds__(256) void k2_edges(
    const float* __restrict__ P, const float* __restrict__ Q,
    const float* __restrict__ b1, const float* __restrict__ g1,
    const float* __restrict__ bt1, const ushort_t* __restrict__ Bpk,
    const float* __restrict__ b2, const float* __restrict__ w3g,
    const float* __restrict__ d2c3, float* __restrict__ logits) {
  __shared__ __align__(16) unsigned char sPlanes[3 * 16384];  // h planes; epi buf aliases
  __shared__ unsigned smeta[BLK_E];
  float* sredE = (float*)sPlanes;                // [64 e][97 words] (24.8 KB)

  const int tid = threadIdx.x;

  // ================= phase A: h1 = LN1(relu(P[si]+Q[so]+b1)) =================
  {
    const int e = tid >> 2;          // edge 0..63
    const int q = tid & 3;           // k-quarter
    int g = blockIdx.x * BLK_E + e;
    int b = g / E_PER_B;
    int t0 = g - b * E_PER_B;
    int si = (int)((1.0 + sqrt(1.0 + 8.0 * (double)t0)) * 0.5);
    while (si * (si - 1) / 2 > t0) --si;
    while ((si + 1) * si / 2 <= t0) ++si;
    int so = t0 - si * (si - 1) / 2;
    if (q == 0) smeta[e] = (unsigned)((b * NN + si) * (NN - 1) + so);

    const float4* P4  = (const float4*)(P + (size_t)(b * NN + si) * 128) + q * 8;
    const float4* Q4  = (const float4*)(Q + (size_t)(b * NN + so) * 128) + q * 8;
    const float4* B14 = (const float4*)b1 + q * 8;
    float av[32];
    float sum = 0.f;
#pragma unroll
    for (int k4 = 0; k4 < 8; ++k4) {
      float4 p = P4[k4], qq = Q4[k4], bb = B14[k4];
      float v0 = fmaxf(p.x + qq.x + bb.x, 0.f);
      float v1 = fmaxf(p.y + qq.y + bb.y, 0.f);
      float v2 = fmaxf(p.z + qq.z + bb.z, 0.f);
      float v3 = fmaxf(p.w + qq.w + bb.w, 0.f);
      av[4 * k4 + 0] = v0; av[4 * k4 + 1] = v1;
      av[4 * k4 + 2] = v2; av[4 * k4 + 3] = v3;
      sum += v0 + v1 + v2 + v3;
    }
    sum += __shfl_xor(sum, 1);
    sum += __shfl_xor(sum, 2);
    float m = sum * 0.0078125f;
    float ss = 0.f;
#pragma unroll
    for (int j = 0; j < 32; ++j) { float dx = av[j] - m; ss += dx * dx; }
    ss += __shfl_xor(ss, 1);
    ss += __shfl_xor(ss, 2);
    float var = ss * 0.0078125f;
    float rs = 1.0f / sqrtf(var + 1e-5f);

    const float4* G14  = (const float4*)g1 + q * 8;
    const float4* BT14 = (const float4*)bt1 + q * 8;
#pragma unroll
    for (int k4 = 0; k4 < 8; ++k4) {
      float4 gg = G14[k4], bt = BT14[k4];
      av[4 * k4 + 0] = (av[4 * k4 + 0] - m) * rs * gg.x + bt.x;
      av[4 * k4 + 1] = (av[4 * k4 + 1] - m) * rs * gg.y + bt.y;
      av[4 * k4 + 2] = (av[4 * k4 + 2] - m) * rs * gg.z + bt.z;
      av[4 * k4 + 3] = (av[4 * k4 + 3] - m) * rs * gg.w + bt.w;
    }
    // split + pack + swizzled store: 4 groups of 8 bf16 per plane
    const unsigned esw = (unsigned)(e & 7);
#pragma unroll
    for (int jj = 0; jj < 4; ++jj) {
      unsigned ph[4], pm[4], pl[4];
#pragma unroll
      for (int ii = 0; ii < 4; ++ii) {
        ushort_t h0, m0, l0, h1x, m1x, l1x;
        split3(av[jj * 8 + 2 * ii],     h0, m0, l0);
        split3(av[jj * 8 + 2 * ii + 1], h1x, m1x, l1x);
        ph[ii] = (unsigned)h0 | ((unsigned)h1x << 16);
        pm[ii] = (unsigned)m0 | ((unsigned)m1x << 16);
        pl[ii] = (unsigned)l0 | ((unsigned)l1x << 16);
      }
      unsigned slot = (unsigned)(4 * q + jj) ^ esw;
      unsigned base = (unsigned)e * 256u + (slot << 4);
      *(uint4*)(sPlanes + base)              = make_uint4(ph[0], ph[1], ph[2], ph[3]);
      *(uint4*)(sPlanes + 16384 + base)      = make_uint4(pm[0], pm[1], pm[2], pm[3]);
      *(uint4*)(sPlanes + 2 * 16384 + base)  = make_uint4(pl[0], pl[1], pl[2], pl[3]);
    }
  }
  __syncthreads();

  // ================= GEMM: h1[64x128] @ W2[128x128], 6-product bf16 =========
  const int w  = tid >> 6;           // wave 0..3
  const int l  = tid & 63;
  const int nc = w;                  // N-strip
  const unsigned lrow = (unsigned)(l & 31);
  const unsigned lk   = (unsigned)(l >> 5);

  f32x16 acc0, acc1;
#pragma unroll
  for (int i = 0; i < 16; ++i) { acc0[i] = 0.f; acc1[i] = 0.f; }

  const unsigned e0 = lrow;
  const unsigned rb0 = e0 * 256u, rb1 = (e0 + 32u) * 256u;
  const unsigned esw = e0 & 7u;
  const unsigned char* pl0 = sPlanes;
  const unsigned char* bpB = (const unsigned char*)Bpk + (unsigned)(nc * 8) * 1024u
                             + (unsigned)l * 16u;
#pragma unroll
  for (int s = 0; s < 8; ++s) {
    bf16x8 bh = *(const bf16x8*)(bpB + (unsigned)s * 1024u);
    bf16x8 bm = *(const bf16x8*)(bpB + 32768 + (unsigned)s * 1024u);
    bf16x8 bl = *(const bf16x8*)(bpB + 2 * 32768 + (unsigned)s * 1024u);
    unsigned co = (((unsigned)(2 * s) + lk) ^ esw) << 4;
    bf16x8 a0h = *(const bf16x8*)(pl0 + rb0 + co);
    bf16x8 a0m = *(const bf16x8*)(pl0 + 16384 + rb0 + co);
    bf16x8 a0l = *(const bf16x8*)(pl0 + 2 * 16384 + rb0 + co);
    bf16x8 a1h = *(const bf16x8*)(pl0 + rb1 + co);
    bf16x8 a1m = *(const bf16x8*)(pl0 + 16384 + rb1 + co);
    bf16x8 a1l = *(const bf16x8*)(pl0 + 2 * 16384 + rb1 + co);
    __builtin_amdgcn_s_setprio(1);
    // smallest-first accumulation
    acc0 = __builtin_amdgcn_mfma_f32_32x32x16_bf16(a0m, bm, acc0, 0, 0, 0);
    acc1 = __builtin_amdgcn_mfma_f32_32x32x16_bf16(a1m, bm, acc1, 0, 0, 0);
    acc0 = __builtin_amdgcn_mfma_f32_32x32x16_bf16(a0l, bh, acc0, 0, 0, 0);
    acc1 = __builtin_amdgcn_mfma_f32_32x32x16_bf16(a1l, bh, acc1, 0, 0, 0);
    acc0 = __builtin_amdgcn_mfma_f32_32x32x16_bf16(a0h, bl, acc0, 0, 0, 0);
    acc1 = __builtin_amdgcn_mfma_f32_32x32x16_bf16(a1h, bl, acc1, 0, 0, 0);
    acc0 = __builtin_amdgcn_mfma_f32_32x32x16_bf16(a0m, bh, acc0, 0, 0, 0);
    acc1 = __builtin_amdgcn_mfma_f32_32x32x16_bf16(a1m, bh, acc1, 0, 0, 0);
    acc0 = __builtin_amdgcn_mfma_f32_32x32x16_bf16(a0h, bm, acc0, 0, 0, 0);
    acc1 = __builtin_amdgcn_mfma_f32_32x32x16_bf16(a1h, bm, acc1, 0, 0, 0);
    acc0 = __builtin_amdgcn_mfma_f32_32x32x16_bf16(a0h, bh, acc0, 0, 0, 0);
    acc1 = __builtin_amdgcn_mfma_f32_32x32x16_bf16(a1h, bh, acc1, 0, 0, 0);
    __builtin_amdgcn_s_setprio(0);
  }
  __syncthreads();   // all A-reads done; planes memory now reusable as sredE

  // ================= epilogue: per-edge stats partials ======================
  {
    const int col = nc * 32 + (int)lrow;
    const float b2c = b2[col];
    const float w3c = w3g[col];
#pragma unroll
    for (int t = 0; t < 2; ++t) {
      const unsigned ebase = (unsigned)t * 32u + 4u * lk;
#pragma unroll
      for (int r = 0; r < 16; ++r) {
        float a = t ? acc1[r] : acc0[r];
        float rr = fmaxf(a + b2c, 0.f);
        float s_ = rr, q_ = rr * rr, d_ = rr * w3c;
        s_ += __shfl_xor(s_, 1); s_ += __shfl_xor(s_, 2);
        q_ += __shfl_xor(q_, 1); q_ += __shfl_xor(q_, 2);
        d_ += __shfl_xor(d_, 1); d_ += __shfl_xor(d_, 2);
        if ((l & 3) == 0) {
          unsigned e = ebase + (unsigned)((r & 3) + 8 * (r >> 2));
          unsigned idx = e * 97u + (unsigned)(nc * 8 + (int)(lrow >> 2)) * 3u;
          sredE[idx]     = s_;
          sredE[idx + 1] = q_;
          sredE[idx + 2] = d_;
        }
      }
    }
  }
  __syncthreads();

  // ================= pass 2: LN2-fold + W3 -> logit =========================
  if (tid < BLK_E) {
    float dd2 = d2c3[0], cc3 = d2c3[1];
    const float* rp = sredE + tid * 97;
    float s = 0.f, q = 0.f, d = 0.f;
#pragma unroll
    for (int j = 0; j < 32; ++j) {
      s += rp[3 * j];
      q += rp[3 * j + 1];
      d += rp[3 * j + 2];
    }
    float m2 = s * 0.0078125f;
    float var = fmaxf(q * 0.0078125f - m2 * m2, 0.f);
    float rs2 = 1.0f / sqrtf(var + 1e-5f);
    logits[smeta[tid]] = rs2 * d - m2 * rs2 * dd2 + cc3;
  }
}

// ---------------- kz: zero output ----------------
__global__ __launch_bounds__(256) void kz_zero(float4* __restrict__ out, int n4) {
  int i = blockIdx.x * 256 + threadIdx.x;
  if (i < n4) out[i] = make_float4(0.f, 0.f, 0.f, 0.f);
}

// ---------------- k3: per (b,i,sample) gumbel argmax -> out=1 ----------------
__global__ __launch_bounds__(320) void k3_argmax(
    const float* __restrict__ logits, float* __restrict__ out) {
  int blk = blockIdx.x;
  int b = blk / NN;
  int i = blk - b * NN;
  if (i == 0) return;                    // row 0's pick lands on the diagonal
  int s = threadIdx.x >> 6;              // sample 0..4 (one wave each)
  int lane = threadIdx.x & 63;
  const float* row = logits + (size_t)(b * NN + i) * (NN - 1);
  float best = -INFINITY;
  int bestj = 0x7fffffff;
  unsigned lbase = ((unsigned)((s * NB + b) * NN + i)) * (NN - 1);
  for (int j = lane; j < i; j += 64) {
    float v = row[j] + gumbel_noise(lbase + (unsigned)j);
    if (v > best) { best = v; bestj = j; }
  }
  for (int off = 32; off; off >>= 1) {
    float ov = __shfl_down(best, off);
    int oj = __shfl_down(bestj, off);
    if (ov > best || (ov == best && oj < bestj)) { best = ov; bestj = oj; }
  }
  if (lane == 0) out[((size_t)(b * NN) + i) * NN + bestj] = 1.0f;
}

// ---------------- launch ----------------
extern "C" void kernel_launch(void* const* d_in, const int* in_sizes, int n_in,
                              void* d_out, int out_size, void* d_ws, size_t ws_size,
                              hipStream_t stream) {
  const float* nodes = (const float*)d_in[0];
  const float* W1  = (const float*)d_in[1];
  const float* b1  = (const float*)d_in[2];
  const float* g1  = (const float*)d_in[3];
  const float* bt1 = (const float*)d_in[4];
  const float* W2  = (const float*)d_in[5];
  const float* b2  = (const float*)d_in[6];
  const float* g2  = (const float*)d_in[7];
  const float* bt2 = (const float*)d_in[8];
  const float* W3  = (const float*)d_in[9];
  const float* b3  = (const float*)d_in[10];

  float* ws     = (float*)d_ws;
  float* Pw     = ws;                 // 393216 floats
  float* Qw     = ws + 393216;        // 393216
  float* w3g    = ws + 786432;        // 128
  float* d2c3   = ws + 786560;        // 2
  float* logits = ws + 786688;        // 1176576
  ushort_t* Bpk = (ushort_t*)(ws + 1963264);  // 49152 bf16 = 96 KB

  hipLaunchKernelGGL(k0_fold, dim3(1), dim3(128), 0, stream, g2, bt2, W3, b3, w3g, d2c3);
  hipLaunchKernelGGL(k0b_split, dim3(64), dim3(256), 0, stream, W2, Bpk);
  hipLaunchKernelGGL(k1_pq, dim3(NB * NN), dim3(128), 0, stream, nodes, W1, Pw, Qw);
  hipLaunchKernelGGL(k2_edges, dim3(E_TOT / BLK_E), dim3(256), 0, stream,
                     Pw, Qw, b1, g1, bt1, Bpk, b2, w3g, d2c3, logits);
  int n4 = out_size / 4;              // 294912
  hipLaunchKernelGGL(kz_zero, dim3((n4 + 255) / 256), dim3(256), 0, stream,
                     (float4*)d_out, n4);
  hipLaunchKernelGGL(k3_argmax, dim3(NB * NN), dim3(320), 0, stream, logits, (float*)d_out);
}

// Round 6
// 328.745 us; speedup vs baseline: 1.2958x; 1.1753x over previous
//
#include <hip/hip_runtime.h>
#include <math.h>

#define E_PER_B 73536
#define E_TOT   588288
#define NB 8
#define NN 384
#define NF 128
#define BLK_E 64

typedef __attribute__((ext_vector_type(8)))  __bf16 bf16x8;
typedef __attribute__((ext_vector_type(16))) float  f32x16;
typedef unsigned short ushort_t;

// ---- threefry2x32, JAX partitionable scheme -> gumbel ----
__device__ __forceinline__ float gumbel_noise(unsigned l) {
  unsigned x0 = 0u;
  unsigned x1 = l;
  const unsigned ks0 = 0u, ks1 = 42u, ks2 = 0x1BD11BDAu ^ 42u;
  x0 += ks0; x1 += ks1;
#define TF_R(r) { x0 += x1; x1 = (x1 << (r)) | (x1 >> (32 - (r))); x1 ^= x0; }
  TF_R(13) TF_R(15) TF_R(26) TF_R(6)
  x0 += ks1; x1 += ks2 + 1u;
  TF_R(17) TF_R(29) TF_R(16) TF_R(24)
  x0 += ks2; x1 += ks0 + 2u;
  TF_R(13) TF_R(15) TF_R(26) TF_R(6)
  x0 += ks0; x1 += ks1 + 3u;
  TF_R(17) TF_R(29) TF_R(16) TF_R(24)
  x0 += ks1; x1 += ks2 + 4u;
  TF_R(13) TF_R(15) TF_R(26) TF_R(6)
  x0 += ks2; x1 += ks0 + 5u;
#undef TF_R
  unsigned bits = x0 ^ x1;
  float u = __uint_as_float((bits >> 9) | 0x3f800000u) - 1.0f;
  u = fmaxf(u, 1.17549435e-38f);
  float t = (float)(-log((double)u));
  return (float)(-log((double)t));
}

// ---- fp32 -> bf16 hi/mid/lo split (RNE for hi/mid, trunc lo) ----
__device__ __forceinline__ void split3(float x, ushort_t& h, ushort_t& m, ushort_t& l) {
  unsigned u = __float_as_uint(x);
  unsigned th = (u + 0x7fffu + ((u >> 16) & 1u)) & 0xffff0000u;
  float hf = __uint_as_float(th);
  float r1 = x - hf;                       // exact (Sterbenz)
  unsigned u1 = __float_as_uint(r1);
  unsigned tm = (u1 + 0x7fffu + ((u1 >> 16) & 1u)) & 0xffff0000u;
  float mf = __uint_as_float(tm);
  float r2 = r1 - mf;                      // exact
  h = (ushort_t)(th >> 16);
  m = (ushort_t)(tm >> 16);
  l = (ushort_t)(__float_as_uint(r2) >> 16);
}

// ---------------- k0: fold LN2 affine into W3 ----------------
__global__ __launch_bounds__(128) void k0_fold(
    const float* __restrict__ g2, const float* __restrict__ bt2,
    const float* __restrict__ W3, const float* __restrict__ b3,
    float* __restrict__ w3g, float* __restrict__ d2c3) {
  __shared__ double red[256];
  int f = threadIdx.x;
  w3g[f] = g2[f] * W3[f];
  red[f]       = (double)g2[f]  * (double)W3[f];
  red[128 + f] = (double)bt2[f] * (double)W3[f];
  __syncthreads();
  if (f == 0) {
    double d2 = 0.0, c3 = 0.0;
    for (int i = 0; i < 128; ++i) { d2 += red[i]; c3 += red[128 + i]; }
    d2c3[0] = (float)d2;
    d2c3[1] = (float)(c3 + (double)b3[0]);
  }
}

// ---------------- k0b: pre-split W2 into packed lane-order B-fragments ----
// Bpk[p][nc][s][l][i] bf16, p=plane(h/m/l), nc=N-strip(4), s=kstep(8),
// l=lane(64), i=reg(8). Element = split_p(W2[k][col]),
// k = s*16 + (l>>5)*8 + i, col = nc*32 + (l&31).
__global__ __launch_bounds__(256) void k0b_split(
    const float* __restrict__ W2, ushort_t* __restrict__ Bpk) {
  int t = blockIdx.x * 256 + threadIdx.x;    // 0..16383
  int k = t >> 7, col = t & 127;
  float x = W2[k * 128 + col];
  ushort_t h, m, l;
  split3(x, h, m, l);
  int nc = col >> 5;
  int ln = (col & 31) + ((k >> 3) & 1) * 32;
  int s  = k >> 4;
  int i  = k & 7;
  int base = ((nc * 8 + s) * 64 + ln) * 8 + i;
  Bpk[base]             = h;
  Bpk[16384 + base]     = m;
  Bpk[2 * 16384 + base] = l;
}

// ---------------- k1: P = nodes@W1[:128], Q = nodes@W1[128:] ----------------
__global__ __launch_bounds__(128) void k1_pq(
    const float* __restrict__ nodes, const float* __restrict__ W1,
    float* __restrict__ P, float* __restrict__ Q) {
  __shared__ float x[128];
  int row = blockIdx.x;
  int f = threadIdx.x;
  x[f] = nodes[row * 128 + f];
  __syncthreads();
  float p = 0.f, q = 0.f;
#pragma unroll 4
  for (int k = 0; k < 128; ++k) {
    float xk = x[k];
    p += xk * W1[k * 128 + f];
    q += xk * W1[(128 + k) * 128 + f];
  }
  P[row * 128 + f] = p;
  Q[row * 128 + f] = q;
}

// ---------------- k2: fused edge MLP (MFMA bf16x3) -> logits ----------------
// 64 edges/block, 256 threads (4 waves), ~49.5 KB LDS -> 3 blocks/CU.
// B-fragments: rolling register prefetch (distance 2; steps 0-1 issued
// before phase A). A-fragments: LDS double-buffered 1 step ahead.
__global__ __launch_bounds__(256, 3) void k2_edges(
    const float* __restrict__ P, const float* __restrict__ Q,
    const float* __restrict__ b1, const float* __restrict__ g1,
    const float* __restrict__ bt1, const ushort_t* __restrict__ Bpk,
    const float* __restrict__ b2, const float* __restrict__ w3g,
    const float* __restrict__ d2c3, float* __restrict__ logits) {
  __shared__ __align__(16) unsigned char sPlanes[3 * 16384];  // h planes; epi buf aliases
  __shared__ unsigned smeta[BLK_E];
  float* sredE = (float*)sPlanes;                // [64 e][97 words] (24.8 KB)

  const int tid = threadIdx.x;
  const int w  = tid >> 6;           // wave 0..3
  const int l  = tid & 63;
  const int nc = w;                  // N-strip
  const unsigned lrow = (unsigned)(l & 31);
  const unsigned lk   = (unsigned)(l >> 5);
  const unsigned char* bpB = (const unsigned char*)Bpk + (unsigned)(nc * 8) * 1024u
                             + (unsigned)l * 16u;

  // ---- B prologue prefetch: steps 0,1 issued before phase A (indep of it) --
  bf16x8 Bh[4], Bm[4], Bl[4];
  Bh[0] = *(const bf16x8*)(bpB);
  Bm[0] = *(const bf16x8*)(bpB + 32768);
  Bl[0] = *(const bf16x8*)(bpB + 65536);
  Bh[1] = *(const bf16x8*)(bpB + 1024);
  Bm[1] = *(const bf16x8*)(bpB + 32768 + 1024);
  Bl[1] = *(const bf16x8*)(bpB + 65536 + 1024);

  // ================= phase A: h1 = LN1(relu(P[si]+Q[so]+b1)) =================
  {
    const int e = tid >> 2;          // edge 0..63
    const int q = tid & 3;           // k-quarter
    int g = blockIdx.x * BLK_E + e;
    int b = g / E_PER_B;
    int t0 = g - b * E_PER_B;
    int si = (int)((1.0 + sqrt(1.0 + 8.0 * (double)t0)) * 0.5);
    while (si * (si - 1) / 2 > t0) --si;
    while ((si + 1) * si / 2 <= t0) ++si;
    int so = t0 - si * (si - 1) / 2;
    if (q == 0) smeta[e] = (unsigned)((b * NN + si) * (NN - 1) + so);

    const float4* P4  = (const float4*)(P + (size_t)(b * NN + si) * 128) + q * 8;
    const float4* Q4  = (const float4*)(Q + (size_t)(b * NN + so) * 128) + q * 8;
    const float4* B14 = (const float4*)b1 + q * 8;
    float av[32];
    float sum = 0.f;
#pragma unroll
    for (int k4 = 0; k4 < 8; ++k4) {
      float4 p = P4[k4], qq = Q4[k4], bb = B14[k4];
      float v0 = fmaxf(p.x + qq.x + bb.x, 0.f);
      float v1 = fmaxf(p.y + qq.y + bb.y, 0.f);
      float v2 = fmaxf(p.z + qq.z + bb.z, 0.f);
      float v3 = fmaxf(p.w + qq.w + bb.w, 0.f);
      av[4 * k4 + 0] = v0; av[4 * k4 + 1] = v1;
      av[4 * k4 + 2] = v2; av[4 * k4 + 3] = v3;
      sum += v0 + v1 + v2 + v3;
    }
    sum += __shfl_xor(sum, 1);
    sum += __shfl_xor(sum, 2);
    float m = sum * 0.0078125f;
    float ss = 0.f;
#pragma unroll
    for (int j = 0; j < 32; ++j) { float dx = av[j] - m; ss += dx * dx; }
    ss += __shfl_xor(ss, 1);
    ss += __shfl_xor(ss, 2);
    float var = ss * 0.0078125f;
    float rs = 1.0f / sqrtf(var + 1e-5f);

    const float4* G14  = (const float4*)g1 + q * 8;
    const float4* BT14 = (const float4*)bt1 + q * 8;
#pragma unroll
    for (int k4 = 0; k4 < 8; ++k4) {
      float4 gg = G14[k4], bt = BT14[k4];
      av[4 * k4 + 0] = (av[4 * k4 + 0] - m) * rs * gg.x + bt.x;
      av[4 * k4 + 1] = (av[4 * k4 + 1] - m) * rs * gg.y + bt.y;
      av[4 * k4 + 2] = (av[4 * k4 + 2] - m) * rs * gg.z + bt.z;
      av[4 * k4 + 3] = (av[4 * k4 + 3] - m) * rs * gg.w + bt.w;
    }
    // split + pack + swizzled store: 4 groups of 8 bf16 per plane
    const unsigned esw = (unsigned)(e & 7);
#pragma unroll
    for (int jj = 0; jj < 4; ++jj) {
      unsigned ph[4], pm[4], pl[4];
#pragma unroll
      for (int ii = 0; ii < 4; ++ii) {
        ushort_t h0, m0, l0, h1x, m1x, l1x;
        split3(av[jj * 8 + 2 * ii],     h0, m0, l0);
        split3(av[jj * 8 + 2 * ii + 1], h1x, m1x, l1x);
        ph[ii] = (unsigned)h0 | ((unsigned)h1x << 16);
        pm[ii] = (unsigned)m0 | ((unsigned)m1x << 16);
        pl[ii] = (unsigned)l0 | ((unsigned)l1x << 16);
      }
      unsigned slot = (unsigned)(4 * q + jj) ^ esw;
      unsigned base = (unsigned)e * 256u + (slot << 4);
      *(uint4*)(sPlanes + base)              = make_uint4(ph[0], ph[1], ph[2], ph[3]);
      *(uint4*)(sPlanes + 16384 + base)      = make_uint4(pm[0], pm[1], pm[2], pm[3]);
      *(uint4*)(sPlanes + 2 * 16384 + base)  = make_uint4(pl[0], pl[1], pl[2], pl[3]);
    }
  }
  __syncthreads();

  // ================= GEMM: h1[64x128] @ W2[128x128], 6-product bf16 =========
  f32x16 acc0, acc1;
#pragma unroll
  for (int i = 0; i < 16; ++i) { acc0[i] = 0.f; acc1[i] = 0.f; }

  const unsigned e0 = lrow;
  const unsigned rb0 = e0 * 256u, rb1 = (e0 + 32u) * 256u;
  const unsigned esw = e0 & 7u;
  const unsigned char* pl0 = sPlanes;

  // A double-buffer: [buf][tile]; prologue loads step 0 into buf 0
  bf16x8 Ah[2][2], Am[2][2], Al[2][2];
  {
    unsigned co = ((0u + lk) ^ esw) << 4;
    Ah[0][0] = *(const bf16x8*)(pl0 + rb0 + co);
    Am[0][0] = *(const bf16x8*)(pl0 + 16384 + rb0 + co);
    Al[0][0] = *(const bf16x8*)(pl0 + 2 * 16384 + rb0 + co);
    Ah[0][1] = *(const bf16x8*)(pl0 + rb1 + co);
    Am[0][1] = *(const bf16x8*)(pl0 + 16384 + rb1 + co);
    Al[0][1] = *(const bf16x8*)(pl0 + 2 * 16384 + rb1 + co);
  }

#pragma unroll
  for (int s = 0; s < 8; ++s) {
    const int cur = s & 1, nxt = (s + 1) & 1;
    // A prefetch for step s+1 (ds_read latency hides under this step's MFMA)
    if (s < 7) {
      unsigned co = (((unsigned)(2 * (s + 1)) + lk) ^ esw) << 4;
      Ah[nxt][0] = *(const bf16x8*)(pl0 + rb0 + co);
      Am[nxt][0] = *(const bf16x8*)(pl0 + 16384 + rb0 + co);
      Al[nxt][0] = *(const bf16x8*)(pl0 + 2 * 16384 + rb0 + co);
      Ah[nxt][1] = *(const bf16x8*)(pl0 + rb1 + co);
      Am[nxt][1] = *(const bf16x8*)(pl0 + 16384 + rb1 + co);
      Al[nxt][1] = *(const bf16x8*)(pl0 + 2 * 16384 + rb1 + co);
    }
    // B prefetch for step s+2 (L2 latency hides under 2 MFMA clusters)
    if (s < 6) {
      Bh[(s + 2) & 3] = *(const bf16x8*)(bpB + (unsigned)(s + 2) * 1024u);
      Bm[(s + 2) & 3] = *(const bf16x8*)(bpB + 32768 + (unsigned)(s + 2) * 1024u);
      Bl[(s + 2) & 3] = *(const bf16x8*)(bpB + 65536 + (unsigned)(s + 2) * 1024u);
    }
    bf16x8 bh = Bh[s & 3], bm = Bm[s & 3], bl = Bl[s & 3];
    __builtin_amdgcn_s_setprio(1);
    // smallest-first accumulation
    acc0 = __builtin_amdgcn_mfma_f32_32x32x16_bf16(Am[cur][0], bm, acc0, 0, 0, 0);
    acc1 = __builtin_amdgcn_mfma_f32_32x32x16_bf16(Am[cur][1], bm, acc1, 0, 0, 0);
    acc0 = __builtin_amdgcn_mfma_f32_32x32x16_bf16(Al[cur][0], bh, acc0, 0, 0, 0);
    acc1 = __builtin_amdgcn_mfma_f32_32x32x16_bf16(Al[cur][1], bh, acc1, 0, 0, 0);
    acc0 = __builtin_amdgcn_mfma_f32_32x32x16_bf16(Ah[cur][0], bl, acc0, 0, 0, 0);
    acc1 = __builtin_amdgcn_mfma_f32_32x32x16_bf16(Ah[cur][1], bl, acc1, 0, 0, 0);
    acc0 = __builtin_amdgcn_mfma_f32_32x32x16_bf16(Am[cur][0], bh, acc0, 0, 0, 0);
    acc1 = __builtin_amdgcn_mfma_f32_32x32x16_bf16(Am[cur][1], bh, acc1, 0, 0, 0);
    acc0 = __builtin_amdgcn_mfma_f32_32x32x16_bf16(Ah[cur][0], bm, acc0, 0, 0, 0);
    acc1 = __builtin_amdgcn_mfma_f32_32x32x16_bf16(Ah[cur][1], bm, acc1, 0, 0, 0);
    acc0 = __builtin_amdgcn_mfma_f32_32x32x16_bf16(Ah[cur][0], bh, acc0, 0, 0, 0);
    acc1 = __builtin_amdgcn_mfma_f32_32x32x16_bf16(Ah[cur][1], bh, acc1, 0, 0, 0);
    __builtin_amdgcn_s_setprio(0);
  }
  __syncthreads();   // all A-reads done; planes memory now reusable as sredE

  // ================= epilogue: per-edge stats partials ======================
  {
    const int col = nc * 32 + (int)lrow;
    const float b2c = b2[col];
    const float w3c = w3g[col];
#pragma unroll
    for (int t = 0; t < 2; ++t) {
      const unsigned ebase = (unsigned)t * 32u + 4u * lk;
#pragma unroll
      for (int r = 0; r < 16; ++r) {
        float a = t ? acc1[r] : acc0[r];
        float rr = fmaxf(a + b2c, 0.f);
        float s_ = rr, q_ = rr * rr, d_ = rr * w3c;
        s_ += __shfl_xor(s_, 1); s_ += __shfl_xor(s_, 2);
        q_ += __shfl_xor(q_, 1); q_ += __shfl_xor(q_, 2);
        d_ += __shfl_xor(d_, 1); d_ += __shfl_xor(d_, 2);
        if ((l & 3) == 0) {
          unsigned e = ebase + (unsigned)((r & 3) + 8 * (r >> 2));
          unsigned idx = e * 97u + (unsigned)(nc * 8 + (int)(lrow >> 2)) * 3u;
          sredE[idx]     = s_;
          sredE[idx + 1] = q_;
          sredE[idx + 2] = d_;
        }
      }
    }
  }
  __syncthreads();

  // ================= pass 2: LN2-fold + W3 -> logit =========================
  if (tid < BLK_E) {
    float dd2 = d2c3[0], cc3 = d2c3[1];
    const float* rp = sredE + tid * 97;
    float s = 0.f, q = 0.f, d = 0.f;
#pragma unroll
    for (int j = 0; j < 32; ++j) {
      s += rp[3 * j];
      q += rp[3 * j + 1];
      d += rp[3 * j + 2];
    }
    float m2 = s * 0.0078125f;
    float var = fmaxf(q * 0.0078125f - m2 * m2, 0.f);
    float rs2 = 1.0f / sqrtf(var + 1e-5f);
    logits[smeta[tid]] = rs2 * d - m2 * rs2 * dd2 + cc3;
  }
}

// ---------------- kz: zero output ----------------
__global__ __launch_bounds__(256) void kz_zero(float4* __restrict__ out, int n4) {
  int i = blockIdx.x * 256 + threadIdx.x;
  if (i < n4) out[i] = make_float4(0.f, 0.f, 0.f, 0.f);
}

// ---------------- k3: per (b,i,sample) gumbel argmax -> out=1 ----------------
__global__ __launch_bounds__(320) void k3_argmax(
    const float* __restrict__ logits, float* __restrict__ out) {
  int blk = blockIdx.x;
  int b = blk / NN;
  int i = blk - b * NN;
  if (i == 0) return;                    // row 0's pick lands on the diagonal
  int s = threadIdx.x >> 6;              // sample 0..4 (one wave each)
  int lane = threadIdx.x & 63;
  const float* row = logits + (size_t)(b * NN + i) * (NN - 1);
  float best = -INFINITY;
  int bestj = 0x7fffffff;
  unsigned lbase = ((unsigned)((s * NB + b) * NN + i)) * (NN - 1);
  for (int j = lane; j < i; j += 64) {
    float v = row[j] + gumbel_noise(lbase + (unsigned)j);
    if (v > best) { best = v; bestj = j; }
  }
  for (int off = 32; off; off >>= 1) {
    float ov = __shfl_down(best, off);
    int oj = __shfl_down(bestj, off);
    if (ov > best || (ov == best && oj < bestj)) { best = ov; bestj = oj; }
  }
  if (lane == 0) out[((size_t)(b * NN) + i) * NN + bestj] = 1.0f;
}

// ---------------- launch ----------------
extern "C" void kernel_launch(void* const* d_in, const int* in_sizes, int n_in,
                              void* d_out, int out_size, void* d_ws, size_t ws_size,
                              hipStream_t stream) {
  const float* nodes = (const float*)d_in[0];
  const float* W1  = (const float*)d_in[1];
  const float* b1  = (const float*)d_in[2];
  const float* g1  = (const float*)d_in[3];
  const float* bt1 = (const float*)d_in[4];
  const float* W2  = (const float*)d_in[5];
  const float* b2  = (const float*)d_in[6];
  const float* g2  = (const float*)d_in[7];
  const float* bt2 = (const float*)d_in[8];
  const float* W3  = (const float*)d_in[9];
  const float* b3  = (const float*)d_in[10];

  float* ws     = (float*)d_ws;
  float* Pw     = ws;                 // 393216 floats
  float* Qw     = ws + 393216;        // 393216
  float* w3g    = ws + 786432;        // 128
  float* d2c3   = ws + 786560;        // 2
  float* logits = ws + 786688;        // 1176576
  ushort_t* Bpk = (ushort_t*)(ws + 1963264);  // 49152 bf16 = 96 KB

  hipLaunchKernelGGL(k0_fold, dim3(1), dim3(128), 0, stream, g2, bt2, W3, b3, w3g, d2c3);
  hipLaunchKernelGGL(k0b_split, dim3(64), dim3(256), 0, stream, W2, Bpk);
  hipLaunchKernelGGL(k1_pq, dim3(NB * NN), dim3(128), 0, stream, nodes, W1, Pw, Qw);
  hipLaunchKernelGGL(k2_edges, dim3(E_TOT / BLK_E), dim3(256), 0, stream,
                     Pw, Qw, b1, g1, bt1, Bpk, b2, w3g, d2c3, logits);
  int n4 = out_size / 4;              // 294912
  hipLaunchKernelGGL(kz_zero, dim3((n4 + 255) / 256), dim3(256), 0, stream,
                     (float4*)d_out, n4);
  hipLaunchKernelGGL(k3_argmax, dim3(NB * NN), dim3(320), 0, stream, logits, (float*)d_out);
}